// Round 12
// baseline (1122.089 us; speedup 1.0000x reference)
//
#include <hip/hip_runtime.h>
#include <cstdint>
#include <cstddef>

// Problem constants
#define B_  512
#define L_  60
#define D_  300
#define H_  256
#define BT  1024          // combined batch (2 branches)
#define KX  320           // D padded to 320 (zeros in pad)
#define KL  576           // LSTM GEMM K: 320 (x) + 256 (h)
#define NG  1024          // 4*H gate width
#define NBLK 512

typedef _Float16 half8   __attribute__((ext_vector_type(8)));
typedef _Float16 half4_t __attribute__((ext_vector_type(4)));
typedef float    floatx4 __attribute__((ext_vector_type(4)));

// v_rcp_f32-based activations (~1ulp rcp; avoids slow exact-div sequence)
__device__ __forceinline__ float fast_tanh(float x){
    float e = __expf(2.f*x);
    return 1.f - 2.f*__builtin_amdgcn_rcpf(e + 1.f);
}
__device__ __forceinline__ float sigm(float x){
    return __builtin_amdgcn_rcpf(1.f + __expf(-x));
}

#define MFMA16(a,b,c) __builtin_amdgcn_mfma_f32_16x16x32_f16(a,b,c,0,0,0)

__global__ void k_fill4(uint4* __restrict__ p, int n4, uint32_t v){
    uint4 q = {v, v, v, v};
    int i = blockIdx.x*blockDim.x + threadIdx.x;
    int st = gridDim.x*blockDim.x;
    for (; i < n4; i += st) p[i] = q;
}

// ---- LPT schedule: sort 1024 rows by cap descending (counting sort, 60 bins),
// pairs of adjacent sorted rows become k_att blocks (longest pairs first).
__global__ void k_sched(const int* __restrict__ s1, const int* __restrict__ s2,
                        int* __restrict__ perm)
{
    __shared__ int bins[61];
    __shared__ int base[61];
    const int tid = threadIdx.x;          // 1024 threads
    if (tid < 61) bins[tid] = 0;
    __syncthreads();
    int cap = (tid < B_) ? s2[tid] : s1[tid - B_];
    atomicAdd(&bins[cap], 1);
    __syncthreads();
    if (tid == 0) {
        int acc = 0;
        for (int c = 60; c >= 1; --c) { base[c] = acc; acc += bins[c]; }
    }
    __syncthreads();
    int pos = atomicAdd(&base[cap], 1);
    perm[pos] = tid;
}

// ================= phase 0: gather X + prep weights =================
__global__ __launch_bounds__(256, 2) void k_prep(
    const float* __restrict__ E,
    const float* __restrict__ Wx1, const float* __restrict__ Wh1,
    const float* __restrict__ Wx2, const float* __restrict__ Wh2,
    const float* __restrict__ W_y, const float* __restrict__ Wh_a, const float* __restrict__ Wr_a,
    const float* __restrict__ Wt_a, const float* __restrict__ Wp_a, const float* __restrict__ Wxa,
    const int* __restrict__ in1, const int* __restrict__ in2,
    _Float16* __restrict__ X16, _Float16* __restrict__ BcatT, _Float16* __restrict__ AW)
{
    const int tid = threadIdx.x;
    const int bid = blockIdx.x;

    for (int it = 0; it < 19; ++it) {
        int gid = it*131072 + bid*256 + tid;
        if (gid < 2457600) {
            int row = gid / (L_*40);
            int rem = gid - row*(L_*40);
            int t  = rem / 40;
            int ch = rem - t*40;
            int k0 = ch*8;
            int tok = (row < B_) ? in1[row*L_ + t] : in2[(row - B_)*L_ + t];
            const float* src = E + (size_t)tok*D_ + k0;
            half8 o;
            #pragma unroll
            for (int k = 0; k < 8; ++k) o[k] = (_Float16)0.f;
            if (k0 + 8 <= D_) {
                float4 a = *(const float4*)(src);
                float4 b = *(const float4*)(src + 4);
                o[0]=(_Float16)a.x; o[1]=(_Float16)a.y; o[2]=(_Float16)a.z; o[3]=(_Float16)a.w;
                o[4]=(_Float16)b.x; o[5]=(_Float16)b.y; o[6]=(_Float16)b.z; o[7]=(_Float16)b.w;
            } else if (k0 < D_) {
                float4 a = *(const float4*)(src);
                o[0]=(_Float16)a.x; o[1]=(_Float16)a.y; o[2]=(_Float16)a.z; o[3]=(_Float16)a.w;
            }
            *(half8*)(X16 + ((size_t)row*L_ + t)*KX + k0) = o;
        }
    }
    for (int it = 0; it < 9; ++it) {
        int idx = it*131072 + bid*256 + tid;     // 9*131072 == 2*KL*NG exactly
        int set = (idx >= KL*NG) ? 1 : 0;
        int rem = idx - set*(KL*NG);
        int k = rem >> 10, n = rem & 1023;
        const float* Wx = set ? Wx2 : Wx1;
        const float* Wh = set ? Wh2 : Wh1;
        float v = 0.f;
        if (k < D_)       v = Wx[k*NG + n];
        else if (k >= KX) v = Wh[(k - KX)*NG + n];
        BcatT[((size_t)set*NG + n)*KL + k] = (_Float16)v;
    }
    for (int it = 0; it < 4; ++it) {
        int idx = it*131072 + bid*256 + tid;
        if (idx < 458752) {
            float v; int dst;
            if (idx < 65536) {
                int k = idx >> 8, n = idx & 255;
                v = W_y[k*256 + n];
                dst = n*256 + k;
            } else if (idx < 131072) {
                int j = idx - 65536; int k = j >> 8, n = j & 255;
                v = Wh_a[k*256 + n];
                dst = 65536 + n*256 + k;
            } else if (idx < 262144) {
                int j = idx - 131072; int n = j >> 8, k = j & 255;
                v = (n < 256) ? Wr_a[k*256 + n] : Wt_a[k*256 + (n - 256)];
                dst = 131072 + n*256 + k;
            } else {
                int j = idx - 262144; int n = j >> 9, k = j & 511;
                v = (k < 256) ? Wp_a[k*256 + n] : Wxa[(k - 256)*256 + n];
                dst = 262144 + n*512 + k;
            }
            AW[dst] = (_Float16)v;
        }
    }
}

// ================= phase 1: LSTM, 60 steps, barrier-free tagged dataflow =================
// ROUND-8 EXACT (proven 533us). Three structural experiments (r7 bulk-issue, r9
// barrier-halving+mi-split, r10 barrier-halving hybrid) ALL regressed: the dense
// per-slab barriers keep the 16 blocks of a row-group lock-stepped so tag polls
// succeed first-try; looser sync -> stale tags -> re-poll traffic and serialization.
// Do not touch this structure.
__global__ __launch_bounds__(256, 2) void k_lstm(
    const float* __restrict__ b1, const float* __restrict__ b2,
    const int* __restrict__ s1, const int* __restrict__ s2,
    const _Float16* __restrict__ X16, _Float16* __restrict__ Y16,
    const _Float16* __restrict__ BcatT,
    unsigned long long* __restrict__ hT, _Float16* __restrict__ hfin)
{
    __shared__ __align__(16) unsigned char shm[33792];

    const int tid = threadIdx.x;
    const int bid = blockIdx.x;
    const int lane = tid & 63, wv = tid >> 6;
    const int q = lane >> 4, lm = lane & 15;

    float (*sG)[64][65] = (float(*)[64][65])shm;      // [2][64][65] epilogue
    _Float16* sA = (_Float16*)shm;                     // [2][64][40] staging (aliased)

    const int ht = bid & 15, mt = bid >> 4;
    const int set = mt >> 4;
    const int m0 = mt*64;
    const int kh = wv >> 1;                 // K-half (0: k<288, 1: k>=288)
    const int wn = (wv & 1)*32;             // col-half
    const int cb = wn >> 4;

    // B fragments in registers, loaded once; pinned so the compiler cannot
    // rematerialize the loads inside the 60-step loop. 72 VGPR: fits, no spill.
    half8 bfr[9][2];
    #pragma unroll
    for (int ch = 0; ch < 9; ++ch)
        #pragma unroll
        for (int ti = 0; ti < 2; ++ti) {
            bfr[ch][ti] = *(const half8*)(BcatT +
                ((size_t)set*NG + (cb+ti)*256 + ht*16 + lm)*KL + kh*288 + ch*32 + q*8);
            asm volatile("" : "+v"(bfr[ch][ti]));
        }

    // A staging map
    const int amA = tid >> 2, kgA = (tid & 3)*8;
    const int pairA = kgA >> 1;             // pair index base (4 pairs per chunk)
    const int rsA = (m0 + amA) & 1023;
    const int xrowA = set ? ((rsA + 512) & 1023) : rsA;

    // epilogue: thread handles h-pair pc and 2 rows (rp passes)
    const float* bias = set ? b2 : b1;
    const int pc = tid & 7;
    const int eh = ht*16 + pc*2;
    float bI[2], bJ[2], bF[2], bO[2];
    #pragma unroll
    for (int j = 0; j < 2; ++j) {
        bI[j] = bias[eh + j]; bJ[j] = bias[256 + eh + j];
        bF[j] = bias[512 + eh + j]; bO[j] = bias[768 + eh + j];
    }
    int esl[2]; float c_st[2][2], h_st[2][2];
    #pragma unroll
    for (int rp = 0; rp < 2; ++rp) {
        int rs = (m0 + (tid >> 3) + rp*32) & 1023;
        esl[rp] = (set == 0) ? ((rs < B_) ? s1[rs] : s2[rs - B_])
                             : ((rs < B_) ? s2[rs] : s1[rs - B_]);
        c_st[rp][0] = 0.f; c_st[rp][1] = 0.f;
        h_st[rp][0] = 0.f; h_st[rp][1] = 0.f;
    }

    half8 zero8;
    #pragma unroll
    for (int k = 0; k < 8; ++k) zero8[k] = (_Float16)0.f;

    for (int t = 0; t < L_; ++t) {
        const _Float16* aX = X16 + ((size_t)xrowA*L_ + t)*KX;
        const unsigned long long* hbase =
            hT + ((size_t)(((t - 1) & 1)*2 + set)*BT + rsA)*128;
        unsigned long long* hTo = hT + (size_t)((t & 1)*2 + set)*BT*128;
        const uint32_t wantTag = (uint32_t)(t - 1);

        floatx4 acc[4][2];
        #pragma unroll
        for (int mi = 0; mi < 4; ++mi)
            #pragma unroll
            for (int ti = 0; ti < 2; ++ti) acc[mi][ti] = (floatx4){0.f,0.f,0.f,0.f};

        half8 av0 = *(const half8*)(aX + kgA);
        half8 av1 = *(const half8*)(aX + 288 + kgA);   // i=0 upper chunk: always X (288..319)
        unsigned long long hw[4];

        #pragma unroll
        for (int i = 0; i < 9; ++i) {
            __syncthreads();
            if (i > 0) {
                if (t > 0) {
                    const unsigned long long* hb = hbase + (i - 1)*16 + pairA;
                    #pragma unroll
                    for (int k = 0; k < 4; ++k) {
                        unsigned long long w = hw[k];
                        while ((uint32_t)(w >> 32) != wantTag)
                            w = __hip_atomic_load(hb + k, __ATOMIC_RELAXED,
                                                  __HIP_MEMORY_SCOPE_AGENT);
                        hw[k] = w;
                    }
                    union { uint32_t u[4]; half8 v; } cv;
                    #pragma unroll
                    for (int k = 0; k < 4; ++k) cv.u[k] = (uint32_t)hw[k];
                    av1 = cv.v;
                } else {
                    av1 = zero8;
                }
            }
            *(half8*)(sA + (     amA)*40 + kgA) = av0;
            *(half8*)(sA + (64 + amA)*40 + kgA) = av1;
            __syncthreads();
            if (i < 8) {
                av0 = *(const half8*)(aX + (i + 1)*32 + kgA);
                if (t > 0) {
                    const unsigned long long* hb = hbase + i*16 + pairA;
                    #pragma unroll
                    for (int k = 0; k < 4; ++k)
                        hw[k] = __hip_atomic_load(hb + k, __ATOMIC_RELAXED,
                                                  __HIP_MEMORY_SCOPE_AGENT);
                }
            }
            half8 af[4];
            #pragma unroll
            for (int mi = 0; mi < 4; ++mi)
                af[mi] = *(const half8*)(sA + (kh*64 + mi*16 + lm)*40 + q*8);
            #pragma unroll
            for (int mi = 0; mi < 4; ++mi) {
                acc[mi][0] = MFMA16(af[mi], bfr[i][0], acc[mi][0]);
                acc[mi][1] = MFMA16(af[mi], bfr[i][1], acc[mi][1]);
            }
        }

        __syncthreads();
        #pragma unroll
        for (int mi = 0; mi < 4; ++mi)
            #pragma unroll
            for (int ti = 0; ti < 2; ++ti)
                #pragma unroll
                for (int r = 0; r < 4; ++r)
                    sG[kh][mi*16 + q*4 + r][wn + ti*16 + lm] = acc[mi][ti][r];
        __syncthreads();

        #pragma unroll
        for (int rp = 0; rp < 2; ++rp) {
            int row = (tid >> 3) + rp*32;
            int gr = m0 + row;
            int rs = gr & 1023;
            bool act = (t < esl[rp]);
            union { _Float16 h[2]; uint32_t u; } hp, yp;
            #pragma unroll
            for (int j = 0; j < 2; ++j) {
                int hh = pc*2 + j;
                float gi = sG[0][row][     hh] + sG[1][row][     hh] + bI[j];
                float gj = sG[0][row][16 + hh] + sG[1][row][16 + hh] + bJ[j];
                float gf = sG[0][row][32 + hh] + sG[1][row][32 + hh] + bF[j];
                float go = sG[0][row][48 + hh] + sG[1][row][48 + hh] + bO[j];
                float c_new = c_st[rp][j]*sigm(gf + 1.f) + sigm(gi)*fast_tanh(gj);
                float h_new = fast_tanh(c_new)*sigm(go);
                if (act) { c_st[rp][j] = c_new; h_st[rp][j] = h_new; }
                hp.h[j] = (_Float16)h_st[rp][j];
                yp.h[j] = act ? (_Float16)h_new : (_Float16)0.f;
            }
            unsigned long long w = ((unsigned long long)(uint32_t)t << 32)
                                 | (unsigned long long)hp.u;
            __hip_atomic_store(hTo + (size_t)rs*128 + (eh >> 1), w,
                               __ATOMIC_RELAXED, __HIP_MEMORY_SCOPE_AGENT);
            if (set == 1 && t == L_ - 1)
                *(uint32_t*)(hfin + (size_t)rs*H_ + eh) = hp.u;
            *(uint32_t*)(Y16 + ((size_t)gr*L_ + t)*H_ + eh) = yp.u;
        }
        // no barrier: dataflow sync via tagged atoms in hT
    }
}

// ================= phase 2: TH only (WyY fused into k_att) =================
// TH = Y2 @ Wh_aT over all 512 blocks: nt = bid&3 (B loaded once), M-tiles
// striped bid>>2 + it*128 over the 960 tiles -> half the old k_wyth duration.
__global__ __launch_bounds__(256, 2) void k_wyth(
    const _Float16* __restrict__ Y16, _Float16* __restrict__ TH16,
    const _Float16* __restrict__ AW)
{
    __shared__ __align__(16) _Float16 sB[64*264];

    const int tid = threadIdx.x;
    const int bid = blockIdx.x;
    const int lane = tid & 63, wv = tid >> 6;
    const int q = lane >> 4, lm = lane & 15;

    const int nt = bid & 3;
    const int n0 = nt*64;
    {
        int rowB = tid >> 2;
        int kb = (tid & 3)*64;
        #pragma unroll
        for (int s = 0; s < 8; ++s)
            *(half8*)(sB + rowB*264 + kb + s*8) =
                *(const half8*)(AW + 65536 + (size_t)(n0 + rowB)*H_ + kb + s*8);
    }
    __syncthreads();
    const _Float16* Ybase = Y16 + (size_t)BT*L_*H_;   // set 1
    for (int it = 0; it < 8; ++it) {
        int m = (bid >> 2) + it*128;
        if (m >= 960) break;
        int m0w = m*64;
        floatx4 acc[4];
        #pragma unroll
        for (int ti = 0; ti < 4; ++ti) acc[ti] = (floatx4){0.f,0.f,0.f,0.f};
        const _Float16* aRow = Ybase + (size_t)(m0w + wv*16 + lm)*H_ + q*8;
        #pragma unroll
        for (int ch = 0; ch < 8; ++ch) {
            half8 a = *(const half8*)(aRow + ch*32);
            #pragma unroll
            for (int ti = 0; ti < 4; ++ti) {
                half8 b = *(const half8*)(sB + (ti*16 + lm)*264 + ch*32 + q*8);
                acc[ti] = MFMA16(a, b, acc[ti]);
            }
        }
        #pragma unroll
        for (int ti = 0; ti < 4; ++ti)
            #pragma unroll
            for (int r = 0; r < 4; ++r)
                TH16[(size_t)(m0w + wv*16 + q*4 + r)*H_ + n0 + ti*16 + lm] = (_Float16)acc[ti][r];
    }
}

// ================= phase 3: persistent attention v6 =================
// Round-8 proven structure + fused WyY: sWy is COMPUTED in the prologue
// (sY @ W_yT via MFMA, B streamed from L2-hot AW) instead of loaded from a
// global WyY16 buffer. Same fragment sequence as old k_wyth -> bit-identical.
__global__ __launch_bounds__(512, 2) void k_att(
    const float* __restrict__ w_a, const int* __restrict__ s1, const int* __restrict__ s2,
    const _Float16* __restrict__ Y16, const _Float16* __restrict__ TH16,
    const _Float16* __restrict__ AW, const int* __restrict__ perm,
    _Float16* __restrict__ rL16)
{
    __shared__ __align__(16) unsigned char shm[141056];

    _Float16* sY  = (_Float16*)shm;                    // [2][60][256]  61440B
    _Float16* sWy = (_Float16*)(shm + 61440);          // [2][60][264]  63360B
    _Float16* sR  = (_Float16*)(shm + 124800);         // [16][264]     8448B  (rows 2-15 zero)
    float*    sTW = (float*)(shm + 133248);            // [2][264]      2112B
    float*    sWt = (float*)(shm + 135360);            // [2][256]      2048B
    float*    sLog= (float*)(shm + 137408);            // [2][64]       512B
    float*    sAl = (float*)(shm + 137920);            // [8][64]       2048B (per-wave copy)
    float*    sWa = (float*)(shm + 139968);            // [256]         1024B
    int*      sU  = (int*)(shm + 140992);              // [2]
    int*      sCap= (int*)(shm + 141000);              // [2]
    int*      sAtt= (int*)(shm + 141008);              // [2]

    const int tid = threadIdx.x;
    const int wv = tid >> 6, lane = tid & 63;
    const int q = lane >> 4, lm = lane & 15;

    if (tid < 2) {
        int u = perm[blockIdx.x*2 + tid];
        sU[tid] = u;
        sCap[tid] = (u < B_) ? s2[u] : s1[u - B_];
        sAtt[tid] = (u < B_) ? s1[u] : s2[u - B_];
    }
    __syncthreads();
    const int uA = sU[0], uB = sU[1];

    if (tid < 256) sWa[tid] = w_a[tid];
    for (int i = tid; i < 16*264; i += 512) sR[i] = (_Float16)0.f;
    for (int i = tid; i < 2*60*32; i += 512) {
        int row = i / 1920;                 // 60*32
        int rem = i - row*1920;
        int l = rem >> 5, ch = rem & 31;
        int u = row ? uB : uA;
        *(half8*)(sY + row*15360 + l*256 + ch*8) =
            *(const half8*)(Y16 + ((size_t)u*L_ + l)*H_ + ch*8);
    }
    __syncthreads();   // sY ready

    // ---- fused WyY: sWy[row][l][n] = sum_k sY[row][l][k] * W_yT[n][k]
    // wave wv owns flattened rows [wv*16, wv*16+16) of the 128-row (2x64) tile.
    {
        const _Float16* WyT = AW;          // [n][k] 256x256 f16 (L2-hot, shared)
        const int rrb = wv*16;
        for (int nt2 = 0; nt2 < 16; ++nt2) {
            floatx4 a4 = (floatx4){0.f,0.f,0.f,0.f};
            #pragma unroll
            for (int ch = 0; ch < 8; ++ch) {
                int rr = rrb + lm;
                half8 a = *(const half8*)(sY + (rr >> 6)*15360 + (rr & 63)*256 + ch*32 + q*8);
                half8 b = *(const half8*)(WyT + (size_t)(nt2*16 + lm)*256 + ch*32 + q*8);
                a4 = MFMA16(a, b, a4);
            }
            #pragma unroll
            for (int r = 0; r < 4; ++r) {
                int rr2 = rrb + q*4 + r;
                int l2 = rr2 & 63;
                if (l2 < 60)
                    sWy[(rr2 >> 6)*15840 + l2*264 + nt2*16 + lm] = (_Float16)a4[r];
            }
        }
    }

    // weight fragments in registers (pinned): wave wv owns cols [64wv, 64wv+64)
    half8 bfr[4][8];
    const _Float16* WrtT = AW + 131072;
    #pragma unroll
    for (int ti = 0; ti < 4; ++ti)
        #pragma unroll
        for (int ch = 0; ch < 8; ++ch) {
            bfr[ti][ch] = *(const half8*)(WrtT + (size_t)((wv*4 + ti)*16 + lm)*256 + ch*32 + q*8);
            asm volatile("" : "+v"(bfr[ti][ch]));
        }
    __syncthreads();   // sWy ready

    const int cap0 = sCap[0], cap1 = sCap[1];
    const int att0 = sAtt[0], att1 = sAtt[1];
    const int mcap = max(cap0, cap1);

    const int rowB = wv >> 2, sB_ = wv & 3;          // score mapping
    const int lsub = lane >> 2, li = lane & 3;
    const int saB = rowB ? att1 : att0;
    const int rowD = tid >> 8, hD = tid & 255;       // output mapping
    const int capD = rowD ? cap1 : cap0;
    const int saD  = rowD ? att1 : att0;
    const int uD   = rowD ? uB : uA;

    // TH prefetch (used by wv<4, q==0 lanes): 4 cols x 2 rows, f16 regs
    const bool thl = (wv < 4) && (q == 0);
    const int  tc0 = (wv*4+0)*16 + lm, tc1 = (wv*4+1)*16 + lm,
               tc2 = (wv*4+2)*16 + lm, tc3 = (wv*4+3)*16 + lm;
    const _Float16* tb0 = TH16 + (size_t)uA*L_*H_;
    const _Float16* tb1 = TH16 + (size_t)uB*L_*H_;
    _Float16 thn[8];
    #pragma unroll
    for (int k = 0; k < 8; ++k) thn[k] = (_Float16)0.f;
    if (thl) {
        thn[0] = tb0[tc0]; thn[1] = tb0[tc1]; thn[2] = tb0[tc2]; thn[3] = tb0[tc3];
        thn[4] = tb1[tc0]; thn[5] = tb1[tc1]; thn[6] = tb1[tc2]; thn[7] = tb1[tc3];
    }

    for (int t = 0; t < mcap; ++t) {
        // ---- A: [W_r r | W_t r] for both rows via one MFMA pass; fold TH; tanh W_t r.
        _Float16 thc[8];
        #pragma unroll
        for (int k = 0; k < 8; ++k) thc[k] = thn[k];
        if (thl && (t + 1 < mcap)) {     // prefetch next step's TH (a full step to land)
            const size_t o = (size_t)(t + 1)*H_;
            thn[0] = tb0[o + tc0]; thn[1] = tb0[o + tc1];
            thn[2] = tb0[o + tc2]; thn[3] = tb0[o + tc3];
            thn[4] = tb1[o + tc0]; thn[5] = tb1[o + tc1];
            thn[6] = tb1[o + tc2]; thn[7] = tb1[o + tc3];
        }
        floatx4 acc[4];
        #pragma unroll
        for (int ti = 0; ti < 4; ++ti) acc[ti] = (floatx4){0.f,0.f,0.f,0.f};
        #pragma unroll
        for (int ch = 0; ch < 8; ++ch) {
            half8 a = *(const half8*)(sR + lm*264 + ch*32 + q*8);
            #pragma unroll
            for (int ti = 0; ti < 4; ++ti)
                acc[ti] = MFMA16(a, bfr[ti][ch], acc[ti]);
        }
        if (q == 0) {
            if (wv < 4) {
                #pragma unroll
                for (int ti = 0; ti < 4; ++ti) {
                    int col = (wv*4 + ti)*16 + lm;
                    sTW[col]       = acc[ti][0] + (float)thc[ti];
                    sTW[264 + col] = acc[ti][1] + (float)thc[4 + ti];
                }
            } else {
                #pragma unroll
                for (int ti = 0; ti < 4; ++ti) {
                    int col = (wv*4 + ti)*16 + lm - 256;
                    sWt[col]       = fast_tanh(acc[ti][0]);
                    sWt[256 + col] = fast_tanh(acc[ti][1]);
                }
            }
        }
        __syncthreads();

        // ---- B: scores. wave handles l = 16*sB_ + lsub of its row; 64 tanh/lane.
        {
            int l = sB_*16 + lsub;
            float v = 0.f;
            if (l < saB) {
                const _Float16* wy = sWy + rowB*15840 + l*264;
                const float* tw = sTW + rowB*264;
                #pragma unroll
                for (int j = 0; j < 16; ++j) {
                    int h0 = j*16 + li*4;
                    half4_t yv = *(const half4_t*)(wy + h0);
                    #pragma unroll
                    for (int k = 0; k < 4; ++k)
                        v += fast_tanh((float)yv[k] + tw[h0 + k]) * sWa[h0 + k];
                }
            }
            v += __shfl_xor(v, 1);
            v += __shfl_xor(v, 2);
            if (li == 0 && l < saB) sLog[rowB*64 + l] = v;
        }
        __syncthreads();

        // ---- C: softmax, computed redundantly by ALL waves for their own row.
        {
            float x = (lane < saB) ? sLog[rowB*64 + lane] : -3.4e38f;
            float m = x;
            #pragma unroll
            for (int off = 32; off > 0; off >>= 1) m = fmaxf(m, __shfl_xor(m, off));
            float e = (lane < saB) ? __expf(x - m) : 0.f;
            float ssum = e;
            #pragma unroll
            for (int off = 32; off > 0; off >>= 1) ssum += __shfl_xor(ssum, off);
            sAl[wv*64 + lane] = e * __builtin_amdgcn_rcpf(ssum);
        }
        // no barrier: D reads only this wave's sAl slice (intra-wave ordering)

        // ---- D: r_new[h] = sum_l alpha[l]*Y[l][h] + tanh(W_t r)[h]
        if (t < capD) {
            const _Float16* yb = sY + rowD*15360 + hD;
            const float* al = sAl + wv*64;
            float a0 = 0.f, a1 = 0.f, a2 = 0.f, a3 = 0.f;
            int l = 0;
            for (; l + 4 <= saD; l += 4) {
                a0 += al[l]     * (float)yb[(size_t)l*256];
                a1 += al[l + 1] * (float)yb[(size_t)(l + 1)*256];
                a2 += al[l + 2] * (float)yb[(size_t)(l + 2)*256];
                a3 += al[l + 3] * (float)yb[(size_t)(l + 3)*256];
            }
            for (; l < saD; ++l) a0 += al[l] * (float)yb[(size_t)l*256];
            float rv = ((a0 + a1) + (a2 + a3)) + sWt[rowD*256 + hD];
            sR[rowD*264 + hD] = (_Float16)rv;
            if (t == capD - 1)
                rL16[(size_t)uD*H_ + hD] = (_Float16)rv;
        }
        __syncthreads();   // sR stable for next step's MFMA; sTW/sWt/sLog reusable
    }
}

// ================= phase 4: ff = [rL | h2] @ (Wp_a|Wxa) =================
__global__ __launch_bounds__(256, 2) void k_ff(
    const _Float16* __restrict__ rL16, const _Float16* __restrict__ hfin,
    const _Float16* __restrict__ AW, float* __restrict__ ff)
{
    __shared__ __align__(16) unsigned char shm[10240];

    const int tid = threadIdx.x;
    const int bid = blockIdx.x;
    const int lane = tid & 63, wv = tid >> 6;
    const int q = lane >> 4, lm = lane & 15;

    _Float16* sA = (_Float16*)shm;
    _Float16* sB = (_Float16*)(shm + 5120);
    const _Float16* WfinT = AW + 262144;
    const int n0 = (bid & 3)*64, m0 = (bid >> 2)*64;
    const int wm = (wv & 1)*32, wn = (wv >> 1)*32;
    const int am = tid >> 2, kg = (tid & 3)*8;
    const int row = m0 + am;
    const _Float16* bRow = WfinT + (size_t)(n0 + am)*512;
    floatx4 acc00 = {0.f,0.f,0.f,0.f}, acc01 = acc00, acc10 = acc00, acc11 = acc00;
    for (int ch = 0; ch < 16; ++ch) {
        const int k0 = ch*32;
        half8 av = (k0 < 256) ? *(const half8*)(rL16 + (size_t)row*H_ + k0 + kg)
                              : *(const half8*)(hfin + (size_t)row*H_ + (k0 - 256) + kg);
        half8 bv = *(const half8*)(bRow + k0 + kg);
        __syncthreads();
        *(half8*)(sA + am*40 + kg) = av;
        *(half8*)(sB + am*40 + kg) = bv;
        __syncthreads();
        half8 a0v = *(const half8*)(sA + (wm + lm)*40 + q*8);
        half8 a1v = *(const half8*)(sA + (wm + 16 + lm)*40 + q*8);
        half8 b0v = *(const half8*)(sB + (wn + lm)*40 + q*8);
        half8 b1v = *(const half8*)(sB + (wn + 16 + lm)*40 + q*8);
        acc00 = MFMA16(a0v, b0v, acc00); acc01 = MFMA16(a0v, b1v, acc01);
        acc10 = MFMA16(a1v, b0v, acc10); acc11 = MFMA16(a1v, b1v, acc11);
    }
    int rb = m0 + wm + q*4, col = n0 + wn + lm;
    #pragma unroll
    for (int r = 0; r < 4; ++r) {
        ff[(size_t)(rb + r)*H_ + col]           = acc00[r];
        ff[(size_t)(rb + r)*H_ + col + 16]      = acc01[r];
        ff[(size_t)(rb + 16 + r)*H_ + col]      = acc10[r];
        ff[(size_t)(rb + 16 + r)*H_ + col + 16] = acc11[r];
    }
}

// ================= phase 5: out = (tanh(ff0)+tanh(ff1)) @ U + b =================
__global__ __launch_bounds__(256, 2) void k_out(
    const float* __restrict__ U, const float* __restrict__ b_o,
    const float* __restrict__ ff, float* __restrict__ out)
{
    __shared__ __align__(16) unsigned char shm[18432];

    const int tid = threadIdx.x;
    const int bid = blockIdx.x;
    const int lane = tid & 63, wv = tid >> 6;

    float* sTh = (float*)shm;            // [16][256]
    float* sU  = (float*)(shm + 16384);  // [512]
    const int b0 = bid*16;
    sU[tid] = U[tid]; sU[256 + tid] = U[256 + tid];
    for (int idx = tid; idx < 16*256; idx += 256) {
        int r = idx >> 8, h = idx & 255;
        sTh[idx] = fast_tanh(ff[(size_t)(b0 + r)*256 + h]) + fast_tanh(ff[(size_t)(b0 + r + 512)*256 + h]);
    }
    __syncthreads();
    for (int r = wv; r < 16; r += 4) {
        float p0 = 0.f, p1 = 0.f;
        #pragma unroll
        for (int k = 0; k < 4; ++k) {
            int h = lane*4 + k;
            float v = sTh[r*256 + h];
            p0 += v * sU[h*2];
            p1 += v * sU[h*2 + 1];
        }
        #pragma unroll
        for (int off = 32; off > 0; off >>= 1) { p0 += __shfl_down(p0, off); p1 += __shfl_down(p1, off); }
        if (lane == 0) {
            out[(b0 + r)*2]     = p0 + b_o[0];
            out[(b0 + r)*2 + 1] = p1 + b_o[1];
        }
    }
}

// ---------------------------------------------------------------- launcher
extern "C" void kernel_launch(void* const* d_in, const int* in_sizes, int n_in,
                              void* d_out, int out_size, void* d_ws, size_t ws_size,
                              hipStream_t stream)
{
    (void)in_sizes; (void)n_in; (void)out_size; (void)ws_size;
    const float* E    = (const float*)d_in[0];
    const float* Wx1  = (const float*)d_in[1];
    const float* Wh1  = (const float*)d_in[2];
    const float* b1   = (const float*)d_in[3];
    const float* Wx2  = (const float*)d_in[4];
    const float* Wh2  = (const float*)d_in[5];
    const float* b2   = (const float*)d_in[6];
    const float* W_y  = (const float*)d_in[7];
    const float* Wh_a = (const float*)d_in[8];
    const float* Wr_a = (const float*)d_in[9];
    const float* w_a  = (const float*)d_in[10];
    const float* Wt_a = (const float*)d_in[11];
    const float* Wp_a = (const float*)d_in[12];
    const float* Wxa  = (const float*)d_in[13];
    const float* U    = (const float*)d_in[14];
    const float* b_o  = (const float*)d_in[15];
    const int* in1 = (const int*)d_in[16];
    const int* in2 = (const int*)d_in[17];
    const int* s1  = (const int*)d_in[18];
    const int* s2  = (const int*)d_in[19];
    float* out = (float*)d_out;

    char* p = (char*)d_ws;
    auto alloc = [&](size_t bytes) { char* r = p; p += (bytes + 255) & ~(size_t)255; return r; };
    _Float16* X16   = (_Float16*)alloc((size_t)BT*L_*KX*2);   // 39.3 MB
    _Float16* Y16   = (_Float16*)alloc(2ull*BT*L_*H_*2);      // 62.9 MB
    _Float16* TH16  = (_Float16*)alloc((size_t)BT*L_*H_*2);   // 31.5 MB
    _Float16* BcatT = (_Float16*)alloc(2ull*NG*KL*2);         // 2.36 MB
    _Float16* AW    = (_Float16*)alloc(393216ull*2);          // 0.79 MB
    unsigned long long* hT = (unsigned long long*)alloc(4ull*BT*128*8);  // 4 MB tagged h
    _Float16* hfin  = (_Float16*)alloc((size_t)BT*H_*2);      // 0.5 MB final h (set 1)
    _Float16* rL16  = (_Float16*)alloc((size_t)BT*H_*2);      // 0.5 MB
    float*    ff    = (float*)   alloc((size_t)BT*H_*4);      // 1 MB
    int*      perm  = (int*)     alloc(4096);                 // LPT row order

    // invalidate all h tags (tag dword becomes 0xFFFFFFFF != any t in [0,60))
    k_fill4<<<256, 256, 0, stream>>>((uint4*)hT, (int)(4ull*BT*128*8/16), 0xFFFFFFFFu);
    k_sched<<<1, 1024, 0, stream>>>(s1, s2, perm);
    k_prep<<<NBLK, 256, 0, stream>>>(E, Wx1, Wh1, Wx2, Wh2,
        W_y, Wh_a, Wr_a, Wt_a, Wp_a, Wxa, in1, in2, X16, BcatT, AW);
    k_lstm<<<NBLK, 256, 0, stream>>>(b1, b2, s1, s2, X16, Y16, BcatT, hT, hfin);
    k_wyth<<<NBLK, 256, 0, stream>>>(Y16, TH16, AW);
    k_att<<<512, 512, 0, stream>>>(w_a, s1, s2, Y16, TH16, AW, perm, rL16);
    k_ff<<<64, 256, 0, stream>>>(rL16, hfin, AW, ff);
    k_out<<<32, 256, 0, stream>>>(U, b_o, ff, out);
}

// Round 13
// 1081.161 us; speedup vs baseline: 1.0379x; 1.0379x over previous
//
#include <hip/hip_runtime.h>
#include <cstdint>
#include <cstddef>

// Problem constants
#define B_  512
#define L_  60
#define D_  300
#define H_  256
#define BT  1024          // combined batch (2 branches)
#define KX  320           // D padded to 320 (zeros in pad)
#define KL  576           // LSTM GEMM K: 320 (x) + 256 (h)
#define NG  1024          // 4*H gate width
#define NBLK 512

typedef _Float16 half8   __attribute__((ext_vector_type(8)));
typedef _Float16 half4_t __attribute__((ext_vector_type(4)));
typedef float    floatx4 __attribute__((ext_vector_type(4)));

// v_rcp_f32-based activations (~1ulp rcp; avoids slow exact-div sequence)
__device__ __forceinline__ float fast_tanh(float x){
    float e = __expf(2.f*x);
    return 1.f - 2.f*__builtin_amdgcn_rcpf(e + 1.f);
}
__device__ __forceinline__ float sigm(float x){
    return __builtin_amdgcn_rcpf(1.f + __expf(-x));
}

#define MFMA16(a,b,c) __builtin_amdgcn_mfma_f32_16x16x32_f16(a,b,c,0,0,0)

__global__ void k_fill4(uint4* __restrict__ p, int n4, uint32_t v){
    uint4 q = {v, v, v, v};
    int i = blockIdx.x*blockDim.x + threadIdx.x;
    int st = gridDim.x*blockDim.x;
    for (; i < n4; i += st) p[i] = q;
}

// ---- LPT schedule: sort 1024 rows by cap descending (counting sort, 60 bins),
// pairs of adjacent sorted rows become k_att blocks (longest pairs first).
__global__ void k_sched(const int* __restrict__ s1, const int* __restrict__ s2,
                        int* __restrict__ perm)
{
    __shared__ int bins[61];
    __shared__ int base[61];
    const int tid = threadIdx.x;          // 1024 threads
    if (tid < 61) bins[tid] = 0;
    __syncthreads();
    int cap = (tid < B_) ? s2[tid] : s1[tid - B_];
    atomicAdd(&bins[cap], 1);
    __syncthreads();
    if (tid == 0) {
        int acc = 0;
        for (int c = 60; c >= 1; --c) { base[c] = acc; acc += bins[c]; }
    }
    __syncthreads();
    int pos = atomicAdd(&base[cap], 1);
    perm[pos] = tid;
}

// ================= phase 0: gather X + prep weights =================
__global__ __launch_bounds__(256, 2) void k_prep(
    const float* __restrict__ E,
    const float* __restrict__ Wx1, const float* __restrict__ Wh1,
    const float* __restrict__ Wx2, const float* __restrict__ Wh2,
    const float* __restrict__ W_y, const float* __restrict__ Wh_a, const float* __restrict__ Wr_a,
    const float* __restrict__ Wt_a, const float* __restrict__ Wp_a, const float* __restrict__ Wxa,
    const int* __restrict__ in1, const int* __restrict__ in2,
    _Float16* __restrict__ X16, _Float16* __restrict__ BcatT, _Float16* __restrict__ AW)
{
    const int tid = threadIdx.x;
    const int bid = blockIdx.x;

    for (int it = 0; it < 19; ++it) {
        int gid = it*131072 + bid*256 + tid;
        if (gid < 2457600) {
            int row = gid / (L_*40);
            int rem = gid - row*(L_*40);
            int t  = rem / 40;
            int ch = rem - t*40;
            int k0 = ch*8;
            int tok = (row < B_) ? in1[row*L_ + t] : in2[(row - B_)*L_ + t];
            const float* src = E + (size_t)tok*D_ + k0;
            half8 o;
            #pragma unroll
            for (int k = 0; k < 8; ++k) o[k] = (_Float16)0.f;
            if (k0 + 8 <= D_) {
                float4 a = *(const float4*)(src);
                float4 b = *(const float4*)(src + 4);
                o[0]=(_Float16)a.x; o[1]=(_Float16)a.y; o[2]=(_Float16)a.z; o[3]=(_Float16)a.w;
                o[4]=(_Float16)b.x; o[5]=(_Float16)b.y; o[6]=(_Float16)b.z; o[7]=(_Float16)b.w;
            } else if (k0 < D_) {
                float4 a = *(const float4*)(src);
                o[0]=(_Float16)a.x; o[1]=(_Float16)a.y; o[2]=(_Float16)a.z; o[3]=(_Float16)a.w;
            }
            *(half8*)(X16 + ((size_t)row*L_ + t)*KX + k0) = o;
        }
    }
    for (int it = 0; it < 9; ++it) {
        int idx = it*131072 + bid*256 + tid;     // 9*131072 == 2*KL*NG exactly
        int set = (idx >= KL*NG) ? 1 : 0;
        int rem = idx - set*(KL*NG);
        int k = rem >> 10, n = rem & 1023;
        const float* Wx = set ? Wx2 : Wx1;
        const float* Wh = set ? Wh2 : Wh1;
        float v = 0.f;
        if (k < D_)       v = Wx[k*NG + n];
        else if (k >= KX) v = Wh[(k - KX)*NG + n];
        BcatT[((size_t)set*NG + n)*KL + k] = (_Float16)v;
    }
    for (int it = 0; it < 4; ++it) {
        int idx = it*131072 + bid*256 + tid;
        if (idx < 458752) {
            float v; int dst;
            if (idx < 65536) {
                int k = idx >> 8, n = idx & 255;
                v = W_y[k*256 + n];
                dst = n*256 + k;
            } else if (idx < 131072) {
                int j = idx - 65536; int k = j >> 8, n = j & 255;
                v = Wh_a[k*256 + n];
                dst = 65536 + n*256 + k;
            } else if (idx < 262144) {
                int j = idx - 131072; int n = j >> 8, k = j & 255;
                v = (n < 256) ? Wr_a[k*256 + n] : Wt_a[k*256 + (n - 256)];
                dst = 131072 + n*256 + k;
            } else {
                int j = idx - 262144; int n = j >> 9, k = j & 511;
                v = (k < 256) ? Wp_a[k*256 + n] : Wxa[(k - 256)*256 + n];
                dst = 262144 + n*512 + k;
            }
            AW[dst] = (_Float16)v;
        }
    }
}

// ================= phase 1: LSTM, 60 steps, barrier-free tagged dataflow =================
// ROUND-8 EXACT (proven 533us). Three structural experiments (r7 bulk-issue, r9
// barrier-halving+mi-split, r10 barrier-halving hybrid) ALL regressed: the dense
// per-slab barriers keep the 16 blocks of a row-group lock-stepped so tag polls
// succeed first-try; looser sync -> stale tags -> re-poll traffic and serialization.
// Do not touch this structure.
__global__ __launch_bounds__(256, 2) void k_lstm(
    const float* __restrict__ b1, const float* __restrict__ b2,
    const int* __restrict__ s1, const int* __restrict__ s2,
    const _Float16* __restrict__ X16, _Float16* __restrict__ Y16,
    const _Float16* __restrict__ BcatT,
    unsigned long long* __restrict__ hT, _Float16* __restrict__ hfin)
{
    __shared__ __align__(16) unsigned char shm[33792];

    const int tid = threadIdx.x;
    const int bid = blockIdx.x;
    const int lane = tid & 63, wv = tid >> 6;
    const int q = lane >> 4, lm = lane & 15;

    float (*sG)[64][65] = (float(*)[64][65])shm;      // [2][64][65] epilogue
    _Float16* sA = (_Float16*)shm;                     // [2][64][40] staging (aliased)

    const int ht = bid & 15, mt = bid >> 4;
    const int set = mt >> 4;
    const int m0 = mt*64;
    const int kh = wv >> 1;                 // K-half (0: k<288, 1: k>=288)
    const int wn = (wv & 1)*32;             // col-half
    const int cb = wn >> 4;

    // B fragments in registers, loaded once; pinned so the compiler cannot
    // rematerialize the loads inside the 60-step loop. 72 VGPR: fits, no spill.
    half8 bfr[9][2];
    #pragma unroll
    for (int ch = 0; ch < 9; ++ch)
        #pragma unroll
        for (int ti = 0; ti < 2; ++ti) {
            bfr[ch][ti] = *(const half8*)(BcatT +
                ((size_t)set*NG + (cb+ti)*256 + ht*16 + lm)*KL + kh*288 + ch*32 + q*8);
            asm volatile("" : "+v"(bfr[ch][ti]));
        }

    // A staging map
    const int amA = tid >> 2, kgA = (tid & 3)*8;
    const int pairA = kgA >> 1;             // pair index base (4 pairs per chunk)
    const int rsA = (m0 + amA) & 1023;
    const int xrowA = set ? ((rsA + 512) & 1023) : rsA;

    // epilogue: thread handles h-pair pc and 2 rows (rp passes)
    const float* bias = set ? b2 : b1;
    const int pc = tid & 7;
    const int eh = ht*16 + pc*2;
    float bI[2], bJ[2], bF[2], bO[2];
    #pragma unroll
    for (int j = 0; j < 2; ++j) {
        bI[j] = bias[eh + j]; bJ[j] = bias[256 + eh + j];
        bF[j] = bias[512 + eh + j]; bO[j] = bias[768 + eh + j];
    }
    int esl[2]; float c_st[2][2], h_st[2][2];
    #pragma unroll
    for (int rp = 0; rp < 2; ++rp) {
        int rs = (m0 + (tid >> 3) + rp*32) & 1023;
        esl[rp] = (set == 0) ? ((rs < B_) ? s1[rs] : s2[rs - B_])
                             : ((rs < B_) ? s2[rs] : s1[rs - B_]);
        c_st[rp][0] = 0.f; c_st[rp][1] = 0.f;
        h_st[rp][0] = 0.f; h_st[rp][1] = 0.f;
    }

    half8 zero8;
    #pragma unroll
    for (int k = 0; k < 8; ++k) zero8[k] = (_Float16)0.f;

    for (int t = 0; t < L_; ++t) {
        const _Float16* aX = X16 + ((size_t)xrowA*L_ + t)*KX;
        const unsigned long long* hbase =
            hT + ((size_t)(((t - 1) & 1)*2 + set)*BT + rsA)*128;
        unsigned long long* hTo = hT + (size_t)((t & 1)*2 + set)*BT*128;
        const uint32_t wantTag = (uint32_t)(t - 1);

        floatx4 acc[4][2];
        #pragma unroll
        for (int mi = 0; mi < 4; ++mi)
            #pragma unroll
            for (int ti = 0; ti < 2; ++ti) acc[mi][ti] = (floatx4){0.f,0.f,0.f,0.f};

        half8 av0 = *(const half8*)(aX + kgA);
        half8 av1 = *(const half8*)(aX + 288 + kgA);   // i=0 upper chunk: always X (288..319)
        unsigned long long hw[4];

        #pragma unroll
        for (int i = 0; i < 9; ++i) {
            __syncthreads();
            if (i > 0) {
                if (t > 0) {
                    const unsigned long long* hb = hbase + (i - 1)*16 + pairA;
                    #pragma unroll
                    for (int k = 0; k < 4; ++k) {
                        unsigned long long w = hw[k];
                        while ((uint32_t)(w >> 32) != wantTag)
                            w = __hip_atomic_load(hb + k, __ATOMIC_RELAXED,
                                                  __HIP_MEMORY_SCOPE_AGENT);
                        hw[k] = w;
                    }
                    union { uint32_t u[4]; half8 v; } cv;
                    #pragma unroll
                    for (int k = 0; k < 4; ++k) cv.u[k] = (uint32_t)hw[k];
                    av1 = cv.v;
                } else {
                    av1 = zero8;
                }
            }
            *(half8*)(sA + (     amA)*40 + kgA) = av0;
            *(half8*)(sA + (64 + amA)*40 + kgA) = av1;
            __syncthreads();
            if (i < 8) {
                av0 = *(const half8*)(aX + (i + 1)*32 + kgA);
                if (t > 0) {
                    const unsigned long long* hb = hbase + i*16 + pairA;
                    #pragma unroll
                    for (int k = 0; k < 4; ++k)
                        hw[k] = __hip_atomic_load(hb + k, __ATOMIC_RELAXED,
                                                  __HIP_MEMORY_SCOPE_AGENT);
                }
            }
            half8 af[4];
            #pragma unroll
            for (int mi = 0; mi < 4; ++mi)
                af[mi] = *(const half8*)(sA + (kh*64 + mi*16 + lm)*40 + q*8);
            #pragma unroll
            for (int mi = 0; mi < 4; ++mi) {
                acc[mi][0] = MFMA16(af[mi], bfr[i][0], acc[mi][0]);
                acc[mi][1] = MFMA16(af[mi], bfr[i][1], acc[mi][1]);
            }
        }

        __syncthreads();
        #pragma unroll
        for (int mi = 0; mi < 4; ++mi)
            #pragma unroll
            for (int ti = 0; ti < 2; ++ti)
                #pragma unroll
                for (int r = 0; r < 4; ++r)
                    sG[kh][mi*16 + q*4 + r][wn + ti*16 + lm] = acc[mi][ti][r];
        __syncthreads();

        #pragma unroll
        for (int rp = 0; rp < 2; ++rp) {
            int row = (tid >> 3) + rp*32;
            int gr = m0 + row;
            int rs = gr & 1023;
            bool act = (t < esl[rp]);
            union { _Float16 h[2]; uint32_t u; } hp, yp;
            #pragma unroll
            for (int j = 0; j < 2; ++j) {
                int hh = pc*2 + j;
                float gi = sG[0][row][     hh] + sG[1][row][     hh] + bI[j];
                float gj = sG[0][row][16 + hh] + sG[1][row][16 + hh] + bJ[j];
                float gf = sG[0][row][32 + hh] + sG[1][row][32 + hh] + bF[j];
                float go = sG[0][row][48 + hh] + sG[1][row][48 + hh] + bO[j];
                float c_new = c_st[rp][j]*sigm(gf + 1.f) + sigm(gi)*fast_tanh(gj);
                float h_new = fast_tanh(c_new)*sigm(go);
                if (act) { c_st[rp][j] = c_new; h_st[rp][j] = h_new; }
                hp.h[j] = (_Float16)h_st[rp][j];
                yp.h[j] = act ? (_Float16)h_new : (_Float16)0.f;
            }
            unsigned long long w = ((unsigned long long)(uint32_t)t << 32)
                                 | (unsigned long long)hp.u;
            __hip_atomic_store(hTo + (size_t)rs*128 + (eh >> 1), w,
                               __ATOMIC_RELAXED, __HIP_MEMORY_SCOPE_AGENT);
            if (set == 1 && t == L_ - 1)
                *(uint32_t*)(hfin + (size_t)rs*H_ + eh) = hp.u;
            *(uint32_t*)(Y16 + ((size_t)gr*L_ + t)*H_ + eh) = yp.u;
        }
        // no barrier: dataflow sync via tagged atoms in hT
    }
}

// ================= phase 2: WyY (z=0) / TH (z=1), B cached in LDS =================
__global__ __launch_bounds__(256, 2) void k_wyth(
    const _Float16* __restrict__ Y16, _Float16* __restrict__ WyY16,
    _Float16* __restrict__ TH16, const _Float16* __restrict__ AW)
{
    __shared__ __align__(16) _Float16 sB[64*264];

    const int tid = threadIdx.x;
    const int bid = blockIdx.x;
    const int lane = tid & 63, wv = tid >> 6;
    const int q = lane >> 4, lm = lane & 15;

    const int slot = bid & 7;
    const int z = slot >> 2, nt = slot & 3;
    const int n0 = nt*64;
    {
        int rowB = tid >> 2;
        int kb = (tid & 3)*64;
        #pragma unroll
        for (int s = 0; s < 8; ++s)
            *(half8*)(sB + rowB*264 + kb + s*8) =
                *(const half8*)(AW + (size_t)z*65536 + (size_t)(n0 + rowB)*H_ + kb + s*8);
    }
    __syncthreads();
    const _Float16* Ybase = Y16 + (size_t)z*((size_t)BT*L_*H_);
    _Float16* dst = z ? TH16 : WyY16;
    for (int mi_ = 0; mi_ < 15; ++mi_) {
        int m0w = ((bid >> 3) + mi_*64)*64;
        floatx4 acc[4];
        #pragma unroll
        for (int ti = 0; ti < 4; ++ti) acc[ti] = (floatx4){0.f,0.f,0.f,0.f};
        const _Float16* aRow = Ybase + (size_t)(m0w + wv*16 + lm)*H_ + q*8;
        #pragma unroll
        for (int ch = 0; ch < 8; ++ch) {
            half8 a = *(const half8*)(aRow + ch*32);
            #pragma unroll
            for (int ti = 0; ti < 4; ++ti) {
                half8 b = *(const half8*)(sB + (ti*16 + lm)*264 + ch*32 + q*8);
                acc[ti] = MFMA16(a, b, acc[ti]);
            }
        }
        #pragma unroll
        for (int ti = 0; ti < 4; ++ti)
            #pragma unroll
            for (int r = 0; r < 4; ++r)
                dst[(size_t)(m0w + wv*16 + q*4 + r)*H_ + n0 + ti*16 + lm] = (_Float16)acc[ti][r];
    }
}

// ================= phase 3: persistent attention v5 (round-8, best) =================
// Redundant per-wave softmax (no softmax->output barrier; 3 barriers/step),
// 4-accumulator ILP in the output dot product, pinned W fragments, LPT pairing.
__global__ __launch_bounds__(512, 2) void k_att(
    const float* __restrict__ w_a, const int* __restrict__ s1, const int* __restrict__ s2,
    const _Float16* __restrict__ Y16, const _Float16* __restrict__ WyY16,
    const _Float16* __restrict__ TH16, const _Float16* __restrict__ AW,
    const int* __restrict__ perm, _Float16* __restrict__ rL16)
{
    __shared__ __align__(16) unsigned char shm[141056];

    _Float16* sY  = (_Float16*)shm;                    // [2][60][256]  61440B
    _Float16* sWy = (_Float16*)(shm + 61440);          // [2][60][264]  63360B
    _Float16* sR  = (_Float16*)(shm + 124800);         // [16][264]     8448B  (rows 2-15 zero)
    float*    sTW = (float*)(shm + 133248);            // [2][264]      2112B
    float*    sWt = (float*)(shm + 135360);            // [2][256]      2048B
    float*    sLog= (float*)(shm + 137408);            // [2][64]       512B
    float*    sAl = (float*)(shm + 137920);            // [8][64]       2048B (per-wave copy)
    float*    sWa = (float*)(shm + 139968);            // [256]         1024B
    int*      sU  = (int*)(shm + 140992);              // [2]
    int*      sCap= (int*)(shm + 141000);              // [2]
    int*      sAtt= (int*)(shm + 141008);              // [2]

    const int tid = threadIdx.x;
    const int wv = tid >> 6, lane = tid & 63;
    const int q = lane >> 4, lm = lane & 15;

    if (tid < 2) {
        int u = perm[blockIdx.x*2 + tid];
        sU[tid] = u;
        sCap[tid] = (u < B_) ? s2[u] : s1[u - B_];
        sAtt[tid] = (u < B_) ? s1[u] : s2[u - B_];
    }
    __syncthreads();
    const int uA = sU[0], uB = sU[1];

    if (tid < 256) sWa[tid] = w_a[tid];
    for (int i = tid; i < 16*264; i += 512) sR[i] = (_Float16)0.f;
    for (int i = tid; i < 2*60*32; i += 512) {
        int row = i / 1920;                 // 60*32
        int rem = i - row*1920;
        int l = rem >> 5, ch = rem & 31;
        int u = row ? uB : uA;
        *(half8*)(sY  + row*15360 + l*256 + ch*8) =
            *(const half8*)(Y16   + ((size_t)u*L_ + l)*H_ + ch*8);
        *(half8*)(sWy + row*15840 + l*264 + ch*8) =
            *(const half8*)(WyY16 + ((size_t)u*L_ + l)*H_ + ch*8);
    }
    // weight fragments in registers (pinned): wave wv owns cols [64wv, 64wv+64)
    half8 bfr[4][8];
    const _Float16* WrtT = AW + 131072;
    #pragma unroll
    for (int ti = 0; ti < 4; ++ti)
        #pragma unroll
        for (int ch = 0; ch < 8; ++ch) {
            bfr[ti][ch] = *(const half8*)(WrtT + (size_t)((wv*4 + ti)*16 + lm)*256 + ch*32 + q*8);
            asm volatile("" : "+v"(bfr[ti][ch]));
        }
    __syncthreads();

    const int cap0 = sCap[0], cap1 = sCap[1];
    const int att0 = sAtt[0], att1 = sAtt[1];
    const int mcap = max(cap0, cap1);

    const int rowB = wv >> 2, sB_ = wv & 3;          // score mapping
    const int lsub = lane >> 2, li = lane & 3;
    const int saB = rowB ? att1 : att0;
    const int rowD = tid >> 8, hD = tid & 255;       // output mapping
    const int capD = rowD ? cap1 : cap0;
    const int saD  = rowD ? att1 : att0;
    const int uD   = rowD ? uB : uA;

    // TH prefetch (used by wv<4, q==0 lanes): 4 cols x 2 rows, f16 regs
    const bool thl = (wv < 4) && (q == 0);
    const int  tc0 = (wv*4+0)*16 + lm, tc1 = (wv*4+1)*16 + lm,
               tc2 = (wv*4+2)*16 + lm, tc3 = (wv*4+3)*16 + lm;
    const _Float16* tb0 = TH16 + (size_t)uA*L_*H_;
    const _Float16* tb1 = TH16 + (size_t)uB*L_*H_;
    _Float16 thn[8];
    #pragma unroll
    for (int k = 0; k < 8; ++k) thn[k] = (_Float16)0.f;
    if (thl) {
        thn[0] = tb0[tc0]; thn[1] = tb0[tc1]; thn[2] = tb0[tc2]; thn[3] = tb0[tc3];
        thn[4] = tb1[tc0]; thn[5] = tb1[tc1]; thn[6] = tb1[tc2]; thn[7] = tb1[tc3];
    }

    for (int t = 0; t < mcap; ++t) {
        // ---- A: [W_r r | W_t r] for both rows via one MFMA pass; fold TH; tanh W_t r.
        _Float16 thc[8];
        #pragma unroll
        for (int k = 0; k < 8; ++k) thc[k] = thn[k];
        if (thl && (t + 1 < mcap)) {     // prefetch next step's TH (a full step to land)
            const size_t o = (size_t)(t + 1)*H_;
            thn[0] = tb0[o + tc0]; thn[1] = tb0[o + tc1];
            thn[2] = tb0[o + tc2]; thn[3] = tb0[o + tc3];
            thn[4] = tb1[o + tc0]; thn[5] = tb1[o + tc1];
            thn[6] = tb1[o + tc2]; thn[7] = tb1[o + tc3];
        }
        floatx4 acc[4];
        #pragma unroll
        for (int ti = 0; ti < 4; ++ti) acc[ti] = (floatx4){0.f,0.f,0.f,0.f};
        #pragma unroll
        for (int ch = 0; ch < 8; ++ch) {
            half8 a = *(const half8*)(sR + lm*264 + ch*32 + q*8);
            #pragma unroll
            for (int ti = 0; ti < 4; ++ti)
                acc[ti] = MFMA16(a, bfr[ti][ch], acc[ti]);
        }
        if (q == 0) {
            if (wv < 4) {
                #pragma unroll
                for (int ti = 0; ti < 4; ++ti) {
                    int col = (wv*4 + ti)*16 + lm;
                    sTW[col]       = acc[ti][0] + (float)thc[ti];
                    sTW[264 + col] = acc[ti][1] + (float)thc[4 + ti];
                }
            } else {
                #pragma unroll
                for (int ti = 0; ti < 4; ++ti) {
                    int col = (wv*4 + ti)*16 + lm - 256;
                    sWt[col]       = fast_tanh(acc[ti][0]);
                    sWt[256 + col] = fast_tanh(acc[ti][1]);
                }
            }
        }
        __syncthreads();

        // ---- B: scores. wave handles l = 16*sB_ + lsub of its row; 64 tanh/lane.
        {
            int l = sB_*16 + lsub;
            float v = 0.f;
            if (l < saB) {
                const _Float16* wy = sWy + rowB*15840 + l*264;
                const float* tw = sTW + rowB*264;
                #pragma unroll
                for (int j = 0; j < 16; ++j) {
                    int h0 = j*16 + li*4;
                    half4_t yv = *(const half4_t*)(wy + h0);
                    #pragma unroll
                    for (int k = 0; k < 4; ++k)
                        v += fast_tanh((float)yv[k] + tw[h0 + k]) * sWa[h0 + k];
                }
            }
            v += __shfl_xor(v, 1);
            v += __shfl_xor(v, 2);
            if (li == 0 && l < saB) sLog[rowB*64 + l] = v;
        }
        __syncthreads();

        // ---- C: softmax, computed redundantly by ALL waves for their own row.
        // Each wave writes its private sAl slice -> intra-wave RAW, no barrier to D.
        {
            float x = (lane < saB) ? sLog[rowB*64 + lane] : -3.4e38f;
            float m = x;
            #pragma unroll
            for (int off = 32; off > 0; off >>= 1) m = fmaxf(m, __shfl_xor(m, off));
            float e = (lane < saB) ? __expf(x - m) : 0.f;
            float ssum = e;
            #pragma unroll
            for (int off = 32; off > 0; off >>= 1) ssum += __shfl_xor(ssum, off);
            sAl[wv*64 + lane] = e * __builtin_amdgcn_rcpf(ssum);
        }
        // no barrier: D reads only this wave's sAl slice (intra-wave ordering)

        // ---- D: r_new[h] = sum_l alpha[l]*Y[l][h] + tanh(W_t r)[h]
        if (t < capD) {
            const _Float16* yb = sY + rowD*15360 + hD;
            const float* al = sAl + wv*64;
            float a0 = 0.f, a1 = 0.f, a2 = 0.f, a3 = 0.f;
            int l = 0;
            for (; l + 4 <= saD; l += 4) {
                a0 += al[l]     * (float)yb[(size_t)l*256];
                a1 += al[l + 1] * (float)yb[(size_t)(l + 1)*256];
                a2 += al[l + 2] * (float)yb[(size_t)(l + 2)*256];
                a3 += al[l + 3] * (float)yb[(size_t)(l + 3)*256];
            }
            for (; l < saD; ++l) a0 += al[l] * (float)yb[(size_t)l*256];
            float rv = ((a0 + a1) + (a2 + a3)) + sWt[rowD*256 + hD];
            sR[rowD*264 + hD] = (_Float16)rv;
            if (t == capD - 1)
                rL16[(size_t)uD*H_ + hD] = (_Float16)rv;
        }
        __syncthreads();   // sR stable for next step's MFMA; sTW/sWt/sLog reusable
    }
}

// ================= phase 4: ff = [rL | h2] @ (Wp_a|Wxa) =================
__global__ __launch_bounds__(256, 2) void k_ff(
    const _Float16* __restrict__ rL16, const _Float16* __restrict__ hfin,
    const _Float16* __restrict__ AW, float* __restrict__ ff)
{
    __shared__ __align__(16) unsigned char shm[10240];

    const int tid = threadIdx.x;
    const int bid = blockIdx.x;
    const int lane = tid & 63, wv = tid >> 6;
    const int q = lane >> 4, lm = lane & 15;

    _Float16* sA = (_Float16*)shm;
    _Float16* sB = (_Float16*)(shm + 5120);
    const _Float16* WfinT = AW + 262144;
    const int n0 = (bid & 3)*64, m0 = (bid >> 2)*64;
    const int wm = (wv & 1)*32, wn = (wv >> 1)*32;
    const int am = tid >> 2, kg = (tid & 3)*8;
    const int row = m0 + am;
    const _Float16* bRow = WfinT + (size_t)(n0 + am)*512;
    floatx4 acc00 = {0.f,0.f,0.f,0.f}, acc01 = acc00, acc10 = acc00, acc11 = acc00;
    for (int ch = 0; ch < 16; ++ch) {
        const int k0 = ch*32;
        half8 av = (k0 < 256) ? *(const half8*)(rL16 + (size_t)row*H_ + k0 + kg)
                              : *(const half8*)(hfin + (size_t)row*H_ + (k0 - 256) + kg);
        half8 bv = *(const half8*)(bRow + k0 + kg);
        __syncthreads();
        *(half8*)(sA + am*40 + kg) = av;
        *(half8*)(sB + am*40 + kg) = bv;
        __syncthreads();
        half8 a0v = *(const half8*)(sA + (wm + lm)*40 + q*8);
        half8 a1v = *(const half8*)(sA + (wm + 16 + lm)*40 + q*8);
        half8 b0v = *(const half8*)(sB + (wn + lm)*40 + q*8);
        half8 b1v = *(const half8*)(sB + (wn + 16 + lm)*40 + q*8);
        acc00 = MFMA16(a0v, b0v, acc00); acc01 = MFMA16(a0v, b1v, acc01);
        acc10 = MFMA16(a1v, b0v, acc10); acc11 = MFMA16(a1v, b1v, acc11);
    }
    int rb = m0 + wm + q*4, col = n0 + wn + lm;
    #pragma unroll
    for (int r = 0; r < 4; ++r) {
        ff[(size_t)(rb + r)*H_ + col]           = acc00[r];
        ff[(size_t)(rb + r)*H_ + col + 16]      = acc01[r];
        ff[(size_t)(rb + 16 + r)*H_ + col]      = acc10[r];
        ff[(size_t)(rb + 16 + r)*H_ + col + 16] = acc11[r];
    }
}

// ================= phase 5: out = (tanh(ff0)+tanh(ff1)) @ U + b =================
__global__ __launch_bounds__(256, 2) void k_out(
    const float* __restrict__ U, const float* __restrict__ b_o,
    const float* __restrict__ ff, float* __restrict__ out)
{
    __shared__ __align__(16) unsigned char shm[18432];

    const int tid = threadIdx.x;
    const int bid = blockIdx.x;
    const int lane = tid & 63, wv = tid >> 6;

    float* sTh = (float*)shm;            // [16][256]
    float* sU  = (float*)(shm + 16384);  // [512]
    const int b0 = bid*16;
    sU[tid] = U[tid]; sU[256 + tid] = U[256 + tid];
    for (int idx = tid; idx < 16*256; idx += 256) {
        int r = idx >> 8, h = idx & 255;
        sTh[idx] = fast_tanh(ff[(size_t)(b0 + r)*256 + h]) + fast_tanh(ff[(size_t)(b0 + r + 512)*256 + h]);
    }
    __syncthreads();
    for (int r = wv; r < 16; r += 4) {
        float p0 = 0.f, p1 = 0.f;
        #pragma unroll
        for (int k = 0; k < 4; ++k) {
            int h = lane*4 + k;
            float v = sTh[r*256 + h];
            p0 += v * sU[h*2];
            p1 += v * sU[h*2 + 1];
        }
        #pragma unroll
        for (int off = 32; off > 0; off >>= 1) { p0 += __shfl_down(p0, off); p1 += __shfl_down(p1, off); }
        if (lane == 0) {
            out[(b0 + r)*2]     = p0 + b_o[0];
            out[(b0 + r)*2 + 1] = p1 + b_o[1];
        }
    }
}

// ---------------------------------------------------------------- launcher
extern "C" void kernel_launch(void* const* d_in, const int* in_sizes, int n_in,
                              void* d_out, int out_size, void* d_ws, size_t ws_size,
                              hipStream_t stream)
{
    (void)in_sizes; (void)n_in; (void)out_size; (void)ws_size;
    const float* E    = (const float*)d_in[0];
    const float* Wx1  = (const float*)d_in[1];
    const float* Wh1  = (const float*)d_in[2];
    const float* b1   = (const float*)d_in[3];
    const float* Wx2  = (const float*)d_in[4];
    const float* Wh2  = (const float*)d_in[5];
    const float* b2   = (const float*)d_in[6];
    const float* W_y  = (const float*)d_in[7];
    const float* Wh_a = (const float*)d_in[8];
    const float* Wr_a = (const float*)d_in[9];
    const float* w_a  = (const float*)d_in[10];
    const float* Wt_a = (const float*)d_in[11];
    const float* Wp_a = (const float*)d_in[12];
    const float* Wxa  = (const float*)d_in[13];
    const float* U    = (const float*)d_in[14];
    const float* b_o  = (const float*)d_in[15];
    const int* in1 = (const int*)d_in[16];
    const int* in2 = (const int*)d_in[17];
    const int* s1  = (const int*)d_in[18];
    const int* s2  = (const int*)d_in[19];
    float* out = (float*)d_out;

    char* p = (char*)d_ws;
    auto alloc = [&](size_t bytes) { char* r = p; p += (bytes + 255) & ~(size_t)255; return r; };
    _Float16* X16   = (_Float16*)alloc((size_t)BT*L_*KX*2);   // 39.3 MB
    _Float16* Y16   = (_Float16*)alloc(2ull*BT*L_*H_*2);      // 62.9 MB
    _Float16* WyY16 = (_Float16*)alloc((size_t)BT*L_*H_*2);   // 31.5 MB
    _Float16* TH16  = (_Float16*)alloc((size_t)BT*L_*H_*2);   // 31.5 MB
    _Float16* BcatT = (_Float16*)alloc(2ull*NG*KL*2);         // 2.36 MB
    _Float16* AW    = (_Float16*)alloc(393216ull*2);          // 0.79 MB
    unsigned long long* hT = (unsigned long long*)alloc(4ull*BT*128*8);  // 4 MB tagged h
    _Float16* hfin  = (_Float16*)alloc((size_t)BT*H_*2);      // 0.5 MB final h (set 1)
    _Float16* rL16  = (_Float16*)alloc((size_t)BT*H_*2);      // 0.5 MB
    float*    ff    = (float*)   alloc((size_t)BT*H_*4);      // 1 MB
    int*      perm  = (int*)     alloc(4096);                 // LPT row order

    // invalidate all h tags (tag dword becomes 0xFFFFFFFF != any t in [0,60))
    k_fill4<<<256, 256, 0, stream>>>((uint4*)hT, (int)(4ull*BT*128*8/16), 0xFFFFFFFFu);
    k_sched<<<1, 1024, 0, stream>>>(s1, s2, perm);
    k_prep<<<NBLK, 256, 0, stream>>>(E, Wx1, Wh1, Wx2, Wh2,
        W_y, Wh_a, Wr_a, Wt_a, Wp_a, Wxa, in1, in2, X16, BcatT, AW);
    k_lstm<<<NBLK, 256, 0, stream>>>(b1, b2, s1, s2, X16, Y16, BcatT, hT, hfin);
    k_wyth<<<NBLK, 256, 0, stream>>>(Y16, WyY16, TH16, AW);
    k_att<<<512, 512, 0, stream>>>(w_a, s1, s2, Y16, WyY16, TH16, AW, perm, rL16);
    k_ff<<<64, 256, 0, stream>>>(rL16, hfin, AW, ff);
    k_out<<<32, 256, 0, stream>>>(U, b_o, ff, out);
}